// Round 2
// baseline (1596.192 us; speedup 1.0000x reference)
//
#include <hip/hip_runtime.h>

// GINConv pipeline, fp32:
//   agg[i] = sum_{e: dst=i} x[src[e]]          (atomic scatter, 102.4M f32 atomics)
//   h1 = (x+agg) @ W1 + b1                      (64x64-tile LDS GEMM, fused col-stats)
//   a_j = gamma*rsqrt(var+eps); c_j = beta - mean*a_j      (1-block finalize)
//   out = relu(h1*a + c) @ W2 + b2              (64x64-tile LDS GEMM, BN/ReLU fused in A-staging)
//
// NOTE: harness delivers integer inputs as int32 (NOT int64, despite the
// reference using int64) — edge_index is const int*.

#define N_NODES 50000
#define N_EDGES 800000
#define D_IN    128
#define D_HID   256
#define D_OUT   128
#define BN_EPS  1e-5f

#define BM 64
#define BN 64

// 32 lanes per edge; each lane handles 4 contiguous channels (float4 gather,
// 4 scalar atomicAdds — atomics are per-dword anyway).
__global__ __launch_bounds__(256) void scatter_kernel(
    const float* __restrict__ x,
    const int* __restrict__ ei,
    float* __restrict__ agg)
{
    const int gtid = blockIdx.x * 256 + threadIdx.x;
    const int eid  = gtid >> 5;
    const int lane = gtid & 31;
    if (eid >= N_EDGES) return;
    const int s = ei[eid];
    const int d = ei[N_EDGES + eid];
    const float4 v = ((const float4*)(x + (size_t)s * D_IN))[lane];
    float* ad = agg + (size_t)d * D_IN + lane * 4;
    atomicAdd(ad + 0, v.x);
    atomicAdd(ad + 1, v.y);
    atomicAdd(ad + 2, v.z);
    atomicAdd(ad + 3, v.w);
}

// h1 = (x+agg) @ W1 + b1, plus per-column sum / sumsq partials for BN.
__global__ __launch_bounds__(256) void gemm1_kernel(
    const float* __restrict__ x, const float* __restrict__ agg,
    const float* __restrict__ W1, const float* __restrict__ b1,
    float* __restrict__ h1, float* __restrict__ ssum, float* __restrict__ ssq)
{
    __shared__ float As[D_IN][BM];   // A transposed: As[k][i]
    __shared__ float Bs[D_IN][BN];   // Bs[k][j]
    const int tid = threadIdx.x;
    const int i0 = blockIdx.x * BM;
    const int jb = blockIdx.y * BN;

    // ---- stage A = (x+agg)^T via 4x4 register transpose (b128 LDS stores, 2-way max) ----
    {
        const int r4 = (tid & 15) * 4;
        const int c8 = (tid >> 4) * 4;
        #pragma unroll
        for (int cc = 0; cc < 2; ++cc) {
            const int c = c8 + cc * 64;
            float4 v[4];
            #pragma unroll
            for (int q = 0; q < 4; ++q) {
                const int row = i0 + r4 + q;
                if (row < N_NODES) {
                    const float4 xv = *(const float4*)(x   + (size_t)row * D_IN + c);
                    const float4 av = *(const float4*)(agg + (size_t)row * D_IN + c);
                    v[q] = make_float4(xv.x+av.x, xv.y+av.y, xv.z+av.z, xv.w+av.w);
                } else {
                    v[q] = make_float4(0.f, 0.f, 0.f, 0.f);
                }
            }
            *(float4*)&As[c+0][r4] = make_float4(v[0].x, v[1].x, v[2].x, v[3].x);
            *(float4*)&As[c+1][r4] = make_float4(v[0].y, v[1].y, v[2].y, v[3].y);
            *(float4*)&As[c+2][r4] = make_float4(v[0].z, v[1].z, v[2].z, v[3].z);
            *(float4*)&As[c+3][r4] = make_float4(v[0].w, v[1].w, v[2].w, v[3].w);
        }
    }
    // ---- stage B = W1[:, jb:jb+64] (coalesced 256B segments) ----
    {
        const int j4 = (tid & 15) * 4;
        const int k0 = tid >> 4;
        #pragma unroll
        for (int kk = 0; kk < 8; ++kk) {
            const int k = k0 + kk * 16;
            *(float4*)&Bs[k][j4] = *(const float4*)(W1 + (size_t)k * D_HID + jb + j4);
        }
    }
    __syncthreads();

    const int tx = tid & 15, ty = tid >> 4;
    const int ay = ty * 4, bx = tx * 4;
    float acc[4][4];
    #pragma unroll
    for (int r = 0; r < 4; ++r)
        #pragma unroll
        for (int q = 0; q < 4; ++q) acc[r][q] = 0.f;

    #pragma unroll 4
    for (int k = 0; k < D_IN; ++k) {
        const float4 a = *(const float4*)&As[k][ay];
        const float4 b = *(const float4*)&Bs[k][bx];
        const float ar[4] = {a.x, a.y, a.z, a.w};
        const float br[4] = {b.x, b.y, b.z, b.w};
        #pragma unroll
        for (int r = 0; r < 4; ++r)
            #pragma unroll
            for (int q = 0; q < 4; ++q)
                acc[r][q] = fmaf(ar[r], br[q], acc[r][q]);
    }

    // ---- epilogue: bias, store h1, per-col partial stats ----
    const float4 b1v = *(const float4*)(b1 + jb + bx);
    const float bvv[4] = {b1v.x, b1v.y, b1v.z, b1v.w};
    float s[4] = {0.f,0.f,0.f,0.f}, sq[4] = {0.f,0.f,0.f,0.f};
    #pragma unroll
    for (int r = 0; r < 4; ++r) {
        const int row = i0 + ay + r;
        if (row < N_NODES) {
            float hv[4];
            #pragma unroll
            for (int q = 0; q < 4; ++q) hv[q] = acc[r][q] + bvv[q];
            *(float4*)(h1 + (size_t)row * D_HID + jb + bx) =
                make_float4(hv[0], hv[1], hv[2], hv[3]);
            #pragma unroll
            for (int q = 0; q < 4; ++q) { s[q] += hv[q]; sq[q] += hv[q]*hv[q]; }
        }
    }
    __syncthreads();                    // reuse As as reduction scratch
    float* red = &As[0][0];             // needs 2*64*16 = 2048 floats
    #pragma unroll
    for (int q = 0; q < 4; ++q) {
        red[(bx + q) * 16 + ty]        = s[q];
        red[1024 + (bx + q) * 16 + ty] = sq[q];
    }
    __syncthreads();
    if (tid < 64) {
        float a0 = 0.f, a1 = 0.f;
        #pragma unroll
        for (int t = 0; t < 16; ++t) {
            a0 += red[tid * 16 + t];
            a1 += red[1024 + tid * 16 + t];
        }
        atomicAdd(&ssum[jb + tid], a0);
        atomicAdd(&ssq [jb + tid], a1);
    }
}

__global__ __launch_bounds__(256) void bnfinal_kernel(
    const float* __restrict__ ssum, const float* __restrict__ ssq,
    const float* __restrict__ gamma, const float* __restrict__ beta,
    float* __restrict__ aco, float* __restrict__ cco)
{
    const int j = threadIdx.x;
    const float inv_n = 1.0f / (float)N_NODES;
    const float mean = ssum[j] * inv_n;
    const float var  = ssq[j] * inv_n - mean * mean;
    const float rstd = rsqrtf(var + BN_EPS);
    const float a = rstd * gamma[j];
    aco[j] = a;
    cco[j] = beta[j] - mean * a;
}

// out = relu(h1*a + c) @ W2 + b2
__global__ __launch_bounds__(256) void gemm2_kernel(
    const float* __restrict__ h1, const float* __restrict__ W2,
    const float* __restrict__ b2,
    const float* __restrict__ aco, const float* __restrict__ cco,
    float* __restrict__ out)
{
    __shared__ float As[128][BM];
    __shared__ float Bs[128][BN];
    const int tid = threadIdx.x;
    const int i0 = blockIdx.x * BM;
    const int jb = blockIdx.y * BN;
    const int tx = tid & 15, ty = tid >> 4;
    const int ay = ty * 4, bx = tx * 4;

    float acc[4][4];
    #pragma unroll
    for (int r = 0; r < 4; ++r)
        #pragma unroll
        for (int q = 0; q < 4; ++q) acc[r][q] = 0.f;

    for (int kk = 0; kk < 2; ++kk) {
        if (kk) __syncthreads();
        // ---- stage A chunk: relu(h1*a + c), transposed ----
        {
            const int r4 = (tid & 15) * 4;
            const int c8 = (tid >> 4) * 4;
            #pragma unroll
            for (int cc = 0; cc < 2; ++cc) {
                const int c  = c8 + cc * 64;
                const int gc = kk * 128 + c;
                const float4 a4 = *(const float4*)(aco + gc);
                const float4 c4 = *(const float4*)(cco + gc);
                float4 v[4];
                #pragma unroll
                for (int q = 0; q < 4; ++q) {
                    const int row = i0 + r4 + q;
                    if (row < N_NODES) {
                        const float4 hv = *(const float4*)(h1 + (size_t)row * D_HID + gc);
                        v[q] = make_float4(fmaxf(fmaf(hv.x, a4.x, c4.x), 0.f),
                                           fmaxf(fmaf(hv.y, a4.y, c4.y), 0.f),
                                           fmaxf(fmaf(hv.z, a4.z, c4.z), 0.f),
                                           fmaxf(fmaf(hv.w, a4.w, c4.w), 0.f));
                    } else {
                        v[q] = make_float4(0.f, 0.f, 0.f, 0.f);
                    }
                }
                *(float4*)&As[c+0][r4] = make_float4(v[0].x, v[1].x, v[2].x, v[3].x);
                *(float4*)&As[c+1][r4] = make_float4(v[0].y, v[1].y, v[2].y, v[3].y);
                *(float4*)&As[c+2][r4] = make_float4(v[0].z, v[1].z, v[2].z, v[3].z);
                *(float4*)&As[c+3][r4] = make_float4(v[0].w, v[1].w, v[2].w, v[3].w);
            }
        }
        // ---- stage B chunk: W2[kk*128 : +128, jb : jb+64] ----
        {
            const int j4 = (tid & 15) * 4;
            const int k0 = tid >> 4;
            #pragma unroll
            for (int kx = 0; kx < 8; ++kx) {
                const int k = k0 + kx * 16;
                *(float4*)&Bs[k][j4] =
                    *(const float4*)(W2 + (size_t)(kk * 128 + k) * D_OUT + jb + j4);
            }
        }
        __syncthreads();

        #pragma unroll 4
        for (int k = 0; k < 128; ++k) {
            const float4 a = *(const float4*)&As[k][ay];
            const float4 b = *(const float4*)&Bs[k][bx];
            const float ar[4] = {a.x, a.y, a.z, a.w};
            const float br[4] = {b.x, b.y, b.z, b.w};
            #pragma unroll
            for (int r = 0; r < 4; ++r)
                #pragma unroll
                for (int q = 0; q < 4; ++q)
                    acc[r][q] = fmaf(ar[r], br[q], acc[r][q]);
        }
    }

    const float4 b2v = *(const float4*)(b2 + jb + bx);
    #pragma unroll
    for (int r = 0; r < 4; ++r) {
        const int row = i0 + ay + r;
        if (row < N_NODES) {
            *(float4*)(out + (size_t)row * D_OUT + jb + bx) =
                make_float4(acc[r][0] + b2v.x, acc[r][1] + b2v.y,
                            acc[r][2] + b2v.z, acc[r][3] + b2v.w);
        }
    }
}

extern "C" void kernel_launch(void* const* d_in, const int* in_sizes, int n_in,
                              void* d_out, int out_size, void* d_ws, size_t ws_size,
                              hipStream_t stream)
{
    const float* x     = (const float*)d_in[0];
    const int*   ei    = (const int*)d_in[1];      // int32 per harness contract
    const float* W1    = (const float*)d_in[2];
    const float* b1    = (const float*)d_in[3];
    const float* gamma = (const float*)d_in[4];
    const float* beta  = (const float*)d_in[5];
    const float* W2    = (const float*)d_in[6];
    const float* b2    = (const float*)d_in[7];
    float* out = (float*)d_out;

    // workspace layout (floats): agg[N*128] | h1[N*256] | ssum[256] | ssq[256] | aco[256] | cco[256]
    float* agg  = (float*)d_ws;
    float* h1   = agg + (size_t)N_NODES * D_IN;
    float* ssum = h1  + (size_t)N_NODES * D_HID;
    float* ssq  = ssum + D_HID;
    float* aco  = ssq  + D_HID;
    float* cco  = aco  + D_HID;

    hipMemsetAsync(agg,  0, (size_t)N_NODES * D_IN * sizeof(float), stream);
    hipMemsetAsync(ssum, 0, 2 * D_HID * sizeof(float), stream);

    scatter_kernel<<<(N_EDGES * 32) / 256, 256, 0, stream>>>(x, ei, agg);

    gemm1_kernel<<<dim3((N_NODES + BM - 1) / BM, D_HID / BN), 256, 0, stream>>>(
        x, agg, W1, b1, h1, ssum, ssq);

    bnfinal_kernel<<<1, D_HID, 0, stream>>>(ssum, ssq, gamma, beta, aco, cco);

    gemm2_kernel<<<dim3((N_NODES + BM - 1) / BM, D_OUT / BN), 256, 0, stream>>>(
        h1, W2, b2, aco, cco, out);
}

// Round 3
// 505.582 us; speedup vs baseline: 3.1571x; 3.1571x over previous
//
#include <hip/hip_runtime.h>

// GINConv pipeline, fp32. R3: replaced 102.4M-atomic scatter (1340us, 84% of
// runtime, WRITE_SIZE 1.6GB = 16B/atomic at coherence point) with on-device
// CSR build + wave-per-node gather-sum (zero f32 atomics).
//
//   deg[d]++ per edge                 (800k int atomics)
//   off = exscan(deg)                 (single 1024-thread block)
//   esrc[off[d]++] = src              (800k int atomics on 200KB cursor)
//   agg[i] = sum_{e in CSR[i]} x[src[e]]   (wave/node, shfl-broadcast indices)
//   h1 = (x+agg) @ W1 + b1            (64x64 LDS GEMM, fused BN col-stats)
//   a = gamma*rsqrt(var+eps); c = beta - mean*a
//   out = relu(h1*a + c) @ W2 + b2    (64x64 LDS GEMM, BN/ReLU fused in A-stage)
//
// NOTE: harness delivers integer inputs as int32 — edge_index is const int*.

#define N_NODES 50000
#define N_EDGES 800000
#define D_IN    128
#define D_HID   256
#define D_OUT   128
#define BN_EPS  1e-5f

#define BM 64
#define BN 64

#define SCAN_T 1024
#define CHUNK  49   // ceil(50000/1024)

__global__ __launch_bounds__(256) void deg_kernel(
    const int* __restrict__ ei, int* __restrict__ deg)
{
    const int e = blockIdx.x * 256 + threadIdx.x;
    if (e >= N_EDGES) return;
    atomicAdd(&deg[ei[N_EDGES + e]], 1);
}

// Single-block exclusive scan: off[0..N], cursor copy for the fill pass.
__global__ __launch_bounds__(SCAN_T) void scan_kernel(
    const int* __restrict__ deg, int* __restrict__ off, int* __restrict__ cursor)
{
    __shared__ int part[SCAN_T];
    const int t = threadIdx.x;
    const int i0 = t * CHUNK;
    const int i1 = min(i0 + CHUNK, N_NODES);
    int s = 0;
    for (int i = i0; i < i1; ++i) s += deg[i];
    part[t] = s;
    __syncthreads();
    // Hillis-Steele inclusive scan
    #pragma unroll
    for (int d = 1; d < SCAN_T; d <<= 1) {
        int v = (t >= d) ? part[t - d] : 0;
        __syncthreads();
        part[t] += v;
        __syncthreads();
    }
    int run = part[t] - s;   // exclusive prefix of this chunk
    for (int i = i0; i < i1; ++i) {
        off[i] = run;
        cursor[i] = run;
        run += deg[i];
    }
    if (t == SCAN_T - 1) off[N_NODES] = run;
}

__global__ __launch_bounds__(256) void fill_kernel(
    const int* __restrict__ ei, int* __restrict__ cursor, int* __restrict__ esrc)
{
    const int e = blockIdx.x * 256 + threadIdx.x;
    if (e >= N_EDGES) return;
    const int pos = atomicAdd(&cursor[ei[N_EDGES + e]], 1);
    esrc[pos] = ei[e];
}

// One wave per node; lane handles 2 channels (float2). Edge indices loaded
// cooperatively (64 at a time) and broadcast via shfl.
__global__ __launch_bounds__(256) void gather_kernel(
    const float* __restrict__ x, const int* __restrict__ off,
    const int* __restrict__ esrc, float* __restrict__ agg)
{
    const int gtid = blockIdx.x * 256 + threadIdx.x;
    const int node = gtid >> 6;
    const int lane = gtid & 63;
    if (node >= N_NODES) return;
    const int e0 = off[node], e1 = off[node + 1];
    float2 acc = make_float2(0.f, 0.f);
    for (int e = e0; e < e1; e += 64) {
        const int n = min(64, e1 - e);
        const int myS = (lane < n) ? esrc[e + lane] : 0;
        for (int j = 0; j < n; ++j) {
            const int s = __shfl(myS, j);
            const float2 v = ((const float2*)(x + (size_t)s * D_IN))[lane];
            acc.x += v.x;
            acc.y += v.y;
        }
    }
    ((float2*)(agg + (size_t)node * D_IN))[lane] = acc;
}

// h1 = (x+agg) @ W1 + b1, plus per-column sum / sumsq partials for BN.
__global__ __launch_bounds__(256) void gemm1_kernel(
    const float* __restrict__ x, const float* __restrict__ agg,
    const float* __restrict__ W1, const float* __restrict__ b1,
    float* __restrict__ h1, float* __restrict__ ssum, float* __restrict__ ssq)
{
    __shared__ float As[D_IN][BM];   // A transposed: As[k][i]
    __shared__ float Bs[D_IN][BN];   // Bs[k][j]
    const int tid = threadIdx.x;
    const int i0 = blockIdx.x * BM;
    const int jb = blockIdx.y * BN;

    // ---- stage A = (x+agg)^T via 4x4 register transpose ----
    {
        const int r4 = (tid & 15) * 4;
        const int c8 = (tid >> 4) * 4;
        #pragma unroll
        for (int cc = 0; cc < 2; ++cc) {
            const int c = c8 + cc * 64;
            float4 v[4];
            #pragma unroll
            for (int q = 0; q < 4; ++q) {
                const int row = i0 + r4 + q;
                if (row < N_NODES) {
                    const float4 xv = *(const float4*)(x   + (size_t)row * D_IN + c);
                    const float4 av = *(const float4*)(agg + (size_t)row * D_IN + c);
                    v[q] = make_float4(xv.x+av.x, xv.y+av.y, xv.z+av.z, xv.w+av.w);
                } else {
                    v[q] = make_float4(0.f, 0.f, 0.f, 0.f);
                }
            }
            *(float4*)&As[c+0][r4] = make_float4(v[0].x, v[1].x, v[2].x, v[3].x);
            *(float4*)&As[c+1][r4] = make_float4(v[0].y, v[1].y, v[2].y, v[3].y);
            *(float4*)&As[c+2][r4] = make_float4(v[0].z, v[1].z, v[2].z, v[3].z);
            *(float4*)&As[c+3][r4] = make_float4(v[0].w, v[1].w, v[2].w, v[3].w);
        }
    }
    // ---- stage B = W1[:, jb:jb+64] ----
    {
        const int j4 = (tid & 15) * 4;
        const int k0 = tid >> 4;
        #pragma unroll
        for (int kk = 0; kk < 8; ++kk) {
            const int k = k0 + kk * 16;
            *(float4*)&Bs[k][j4] = *(const float4*)(W1 + (size_t)k * D_HID + jb + j4);
        }
    }
    __syncthreads();

    const int tx = tid & 15, ty = tid >> 4;
    const int ay = ty * 4, bx = tx * 4;
    float acc[4][4];
    #pragma unroll
    for (int r = 0; r < 4; ++r)
        #pragma unroll
        for (int q = 0; q < 4; ++q) acc[r][q] = 0.f;

    #pragma unroll 4
    for (int k = 0; k < D_IN; ++k) {
        const float4 a = *(const float4*)&As[k][ay];
        const float4 b = *(const float4*)&Bs[k][bx];
        const float ar[4] = {a.x, a.y, a.z, a.w};
        const float br[4] = {b.x, b.y, b.z, b.w};
        #pragma unroll
        for (int r = 0; r < 4; ++r)
            #pragma unroll
            for (int q = 0; q < 4; ++q)
                acc[r][q] = fmaf(ar[r], br[q], acc[r][q]);
    }

    // ---- epilogue: bias, store h1, per-col partial stats ----
    const float4 b1v = *(const float4*)(b1 + jb + bx);
    const float bvv[4] = {b1v.x, b1v.y, b1v.z, b1v.w};
    float s[4] = {0.f,0.f,0.f,0.f}, sq[4] = {0.f,0.f,0.f,0.f};
    #pragma unroll
    for (int r = 0; r < 4; ++r) {
        const int row = i0 + ay + r;
        if (row < N_NODES) {
            float hv[4];
            #pragma unroll
            for (int q = 0; q < 4; ++q) hv[q] = acc[r][q] + bvv[q];
            *(float4*)(h1 + (size_t)row * D_HID + jb + bx) =
                make_float4(hv[0], hv[1], hv[2], hv[3]);
            #pragma unroll
            for (int q = 0; q < 4; ++q) { s[q] += hv[q]; sq[q] += hv[q]*hv[q]; }
        }
    }
    __syncthreads();                    // reuse As as reduction scratch
    float* red = &As[0][0];             // needs 2*64*16 = 2048 floats
    #pragma unroll
    for (int q = 0; q < 4; ++q) {
        red[(bx + q) * 16 + ty]        = s[q];
        red[1024 + (bx + q) * 16 + ty] = sq[q];
    }
    __syncthreads();
    if (tid < 64) {
        float a0 = 0.f, a1 = 0.f;
        #pragma unroll
        for (int t = 0; t < 16; ++t) {
            a0 += red[tid * 16 + t];
            a1 += red[1024 + tid * 16 + t];
        }
        atomicAdd(&ssum[jb + tid], a0);
        atomicAdd(&ssq [jb + tid], a1);
    }
}

__global__ __launch_bounds__(256) void bnfinal_kernel(
    const float* __restrict__ ssum, const float* __restrict__ ssq,
    const float* __restrict__ gamma, const float* __restrict__ beta,
    float* __restrict__ aco, float* __restrict__ cco)
{
    const int j = threadIdx.x;
    const float inv_n = 1.0f / (float)N_NODES;
    const float mean = ssum[j] * inv_n;
    const float var  = ssq[j] * inv_n - mean * mean;
    const float rstd = rsqrtf(var + BN_EPS);
    const float a = rstd * gamma[j];
    aco[j] = a;
    cco[j] = beta[j] - mean * a;
}

// out = relu(h1*a + c) @ W2 + b2
__global__ __launch_bounds__(256) void gemm2_kernel(
    const float* __restrict__ h1, const float* __restrict__ W2,
    const float* __restrict__ b2,
    const float* __restrict__ aco, const float* __restrict__ cco,
    float* __restrict__ out)
{
    __shared__ float As[128][BM];
    __shared__ float Bs[128][BN];
    const int tid = threadIdx.x;
    const int i0 = blockIdx.x * BM;
    const int jb = blockIdx.y * BN;
    const int tx = tid & 15, ty = tid >> 4;
    const int ay = ty * 4, bx = tx * 4;

    float acc[4][4];
    #pragma unroll
    for (int r = 0; r < 4; ++r)
        #pragma unroll
        for (int q = 0; q < 4; ++q) acc[r][q] = 0.f;

    for (int kk = 0; kk < 2; ++kk) {
        if (kk) __syncthreads();
        // ---- stage A chunk: relu(h1*a + c), transposed ----
        {
            const int r4 = (tid & 15) * 4;
            const int c8 = (tid >> 4) * 4;
            #pragma unroll
            for (int cc = 0; cc < 2; ++cc) {
                const int c  = c8 + cc * 64;
                const int gc = kk * 128 + c;
                const float4 a4 = *(const float4*)(aco + gc);
                const float4 c4 = *(const float4*)(cco + gc);
                float4 v[4];
                #pragma unroll
                for (int q = 0; q < 4; ++q) {
                    const int row = i0 + r4 + q;
                    if (row < N_NODES) {
                        const float4 hv = *(const float4*)(h1 + (size_t)row * D_HID + gc);
                        v[q] = make_float4(fmaxf(fmaf(hv.x, a4.x, c4.x), 0.f),
                                           fmaxf(fmaf(hv.y, a4.y, c4.y), 0.f),
                                           fmaxf(fmaf(hv.z, a4.z, c4.z), 0.f),
                                           fmaxf(fmaf(hv.w, a4.w, c4.w), 0.f));
                    } else {
                        v[q] = make_float4(0.f, 0.f, 0.f, 0.f);
                    }
                }
                *(float4*)&As[c+0][r4] = make_float4(v[0].x, v[1].x, v[2].x, v[3].x);
                *(float4*)&As[c+1][r4] = make_float4(v[0].y, v[1].y, v[2].y, v[3].y);
                *(float4*)&As[c+2][r4] = make_float4(v[0].z, v[1].z, v[2].z, v[3].z);
                *(float4*)&As[c+3][r4] = make_float4(v[0].w, v[1].w, v[2].w, v[3].w);
            }
        }
        // ---- stage B chunk: W2[kk*128 : +128, jb : jb+64] ----
        {
            const int j4 = (tid & 15) * 4;
            const int k0 = tid >> 4;
            #pragma unroll
            for (int kx = 0; kx < 8; ++kx) {
                const int k = k0 + kx * 16;
                *(float4*)&Bs[k][j4] =
                    *(const float4*)(W2 + (size_t)(kk * 128 + k) * D_OUT + jb + j4);
            }
        }
        __syncthreads();

        #pragma unroll 4
        for (int k = 0; k < 128; ++k) {
            const float4 a = *(const float4*)&As[k][ay];
            const float4 b = *(const float4*)&Bs[k][bx];
            const float ar[4] = {a.x, a.y, a.z, a.w};
            const float br[4] = {b.x, b.y, b.z, b.w};
            #pragma unroll
            for (int r = 0; r < 4; ++r)
                #pragma unroll
                for (int q = 0; q < 4; ++q)
                    acc[r][q] = fmaf(ar[r], br[q], acc[r][q]);
        }
    }

    const float4 b2v = *(const float4*)(b2 + jb + bx);
    #pragma unroll
    for (int r = 0; r < 4; ++r) {
        const int row = i0 + ay + r;
        if (row < N_NODES) {
            *(float4*)(out + (size_t)row * D_OUT + jb + bx) =
                make_float4(acc[r][0] + b2v.x, acc[r][1] + b2v.y,
                            acc[r][2] + b2v.z, acc[r][3] + b2v.w);
        }
    }
}

extern "C" void kernel_launch(void* const* d_in, const int* in_sizes, int n_in,
                              void* d_out, int out_size, void* d_ws, size_t ws_size,
                              hipStream_t stream)
{
    const float* x     = (const float*)d_in[0];
    const int*   ei    = (const int*)d_in[1];      // int32 per harness contract
    const float* W1    = (const float*)d_in[2];
    const float* b1    = (const float*)d_in[3];
    const float* gamma = (const float*)d_in[4];
    const float* beta  = (const float*)d_in[5];
    const float* W2    = (const float*)d_in[6];
    const float* b2    = (const float*)d_in[7];
    float* out = (float*)d_out;

    // workspace layout (floats/ints):
    // agg[N*128] | h1[N*256] | ssum[256] | ssq[256] | aco[256] | cco[256]
    // | deg[N] | off[N+1] | cursor[N] | esrc[E]
    float* agg  = (float*)d_ws;
    float* h1   = agg + (size_t)N_NODES * D_IN;
    float* ssum = h1  + (size_t)N_NODES * D_HID;
    float* ssq  = ssum + D_HID;
    float* aco  = ssq  + D_HID;
    float* cco  = aco  + D_HID;
    int* deg    = (int*)(cco + D_HID);
    int* off    = deg + N_NODES;
    int* cursor = off + N_NODES + 1;
    int* esrc   = cursor + N_NODES;

    hipMemsetAsync(deg,  0, N_NODES * sizeof(int), stream);
    hipMemsetAsync(ssum, 0, 2 * D_HID * sizeof(float), stream);

    deg_kernel<<<(N_EDGES + 255) / 256, 256, 0, stream>>>(ei, deg);
    scan_kernel<<<1, SCAN_T, 0, stream>>>(deg, off, cursor);
    fill_kernel<<<(N_EDGES + 255) / 256, 256, 0, stream>>>(ei, cursor, esrc);
    gather_kernel<<<(N_NODES * 64 + 255) / 256, 256, 0, stream>>>(x, off, esrc, agg);

    gemm1_kernel<<<dim3((N_NODES + BM - 1) / BM, D_HID / BN), 256, 0, stream>>>(
        x, agg, W1, b1, h1, ssum, ssq);

    bnfinal_kernel<<<1, D_HID, 0, stream>>>(ssum, ssq, gamma, beta, aco, cco);

    gemm2_kernel<<<dim3((N_NODES + BM - 1) / BM, D_OUT / BN), 256, 0, stream>>>(
        h1, W2, b2, aco, cco, out);
}

// Round 4
// 397.580 us; speedup vs baseline: 4.0148x; 1.2716x over previous
//
#include <hip/hip_runtime.h>

// GINConv pipeline, fp32. R4: replaced the single-block 111us scan (one CU,
// latency-bound, Occupancy 0.14%) with a 3-phase grid-parallel scan.
//
//   deg[d]++ per edge                  (800k int atomics)
//   off = exscan(deg)                  (49-block sums -> 1-wave scan -> apply)
//   esrc[off[d]++] = src               (800k int atomics on 200KB cursor)
//   agg[i] = sum_{e in CSR[i]} x[src[e]]   (wave/node, shfl-broadcast indices)
//   h1 = (x+agg) @ W1 + b1             (64x64 LDS GEMM, fused BN col-stats)
//   a = gamma*rsqrt(var+eps); c = beta - mean*a
//   out = relu(h1*a + c) @ W2 + b2     (64x64 LDS GEMM, BN/ReLU fused in A-stage)
//
// NOTE: harness delivers integer inputs as int32 — edge_index is const int*.

#define N_NODES 50000
#define N_EDGES 800000
#define D_IN    128
#define D_HID   256
#define D_OUT   128
#define BN_EPS  1e-5f

#define BM 64
#define BN 64

#define NBLK_SCAN 49   // ceil(50000 / 1024)

__global__ __launch_bounds__(256) void deg_kernel(
    const int* __restrict__ ei, int* __restrict__ deg)
{
    const int e = blockIdx.x * 256 + threadIdx.x;
    if (e >= N_EDGES) return;
    atomicAdd(&deg[ei[N_EDGES + e]], 1);
}

// Phase 1: per-block (1024 elems) sums.
__global__ __launch_bounds__(256) void scan1_kernel(
    const int* __restrict__ deg, int* __restrict__ bsum)
{
    __shared__ int ws[4];
    const int t = threadIdx.x;
    const int i0 = blockIdx.x * 1024 + t * 4;
    int s = 0;
    if (i0 + 3 < N_NODES) {
        const int4 d = *(const int4*)(deg + i0);
        s = d.x + d.y + d.z + d.w;
    } else {
        #pragma unroll
        for (int q = 0; q < 4; ++q) if (i0 + q < N_NODES) s += deg[i0 + q];
    }
    #pragma unroll
    for (int d = 32; d > 0; d >>= 1) s += __shfl_down(s, d);
    if ((t & 63) == 0) ws[t >> 6] = s;
    __syncthreads();
    if (t == 0) bsum[blockIdx.x] = ws[0] + ws[1] + ws[2] + ws[3];
}

// Phase 2: 1-wave exclusive scan of the 49 block sums (in place).
__global__ __launch_bounds__(64) void scan2_kernel(
    int* __restrict__ bsum, int* __restrict__ off)
{
    const int lane = threadIdx.x;
    const int v = (lane < NBLK_SCAN) ? bsum[lane] : 0;
    int incl = v;
    #pragma unroll
    for (int d = 1; d < 64; d <<= 1) {
        const int up = __shfl_up(incl, d);
        if (lane >= d) incl += up;
    }
    if (lane < NBLK_SCAN) bsum[lane] = incl - v;
    if (lane == 0) off[N_NODES] = N_EDGES;   // total is a constant
}

// Phase 3: in-block scan + block base -> off[] and cursor[].
__global__ __launch_bounds__(256) void scan3_kernel(
    const int* __restrict__ deg, const int* __restrict__ bsum,
    int* __restrict__ off, int* __restrict__ cursor)
{
    __shared__ int ws[4];
    const int t = threadIdx.x;
    const int lane = t & 63, wid = t >> 6;
    const int i0 = blockIdx.x * 1024 + t * 4;
    int4 d = make_int4(0, 0, 0, 0);
    if (i0 + 3 < N_NODES) {
        d = *(const int4*)(deg + i0);
    } else {
        if (i0 + 0 < N_NODES) d.x = deg[i0 + 0];
        if (i0 + 1 < N_NODES) d.y = deg[i0 + 1];
        if (i0 + 2 < N_NODES) d.z = deg[i0 + 2];
    }
    const int tsum = d.x + d.y + d.z + d.w;
    int incl = tsum;
    #pragma unroll
    for (int dd = 1; dd < 64; dd <<= 1) {
        const int up = __shfl_up(incl, dd);
        if (lane >= dd) incl += up;
    }
    if (lane == 63) ws[wid] = incl;
    __syncthreads();
    int wbase = 0;
    for (int w = 0; w < wid; ++w) wbase += ws[w];
    const int e = bsum[blockIdx.x] + wbase + incl - tsum;
    int4 o;
    o.x = e; o.y = e + d.x; o.z = o.y + d.y; o.w = o.z + d.z;
    if (i0 + 3 < N_NODES) {
        *(int4*)(off + i0)    = o;
        *(int4*)(cursor + i0) = o;
    } else {
        if (i0 + 0 < N_NODES) { off[i0 + 0] = o.x; cursor[i0 + 0] = o.x; }
        if (i0 + 1 < N_NODES) { off[i0 + 1] = o.y; cursor[i0 + 1] = o.y; }
        if (i0 + 2 < N_NODES) { off[i0 + 2] = o.z; cursor[i0 + 2] = o.z; }
    }
}

__global__ __launch_bounds__(256) void fill_kernel(
    const int* __restrict__ ei, int* __restrict__ cursor, int* __restrict__ esrc)
{
    const int e = blockIdx.x * 256 + threadIdx.x;
    if (e >= N_EDGES) return;
    const int pos = atomicAdd(&cursor[ei[N_EDGES + e]], 1);
    esrc[pos] = ei[e];
}

// One wave per node; lane handles 2 channels (float2). Edge indices loaded
// cooperatively (64 at a time) and broadcast via shfl.
__global__ __launch_bounds__(256) void gather_kernel(
    const float* __restrict__ x, const int* __restrict__ off,
    const int* __restrict__ esrc, float* __restrict__ agg)
{
    const int gtid = blockIdx.x * 256 + threadIdx.x;
    const int node = gtid >> 6;
    const int lane = gtid & 63;
    if (node >= N_NODES) return;
    const int e0 = off[node], e1 = off[node + 1];
    float2 acc = make_float2(0.f, 0.f);
    for (int e = e0; e < e1; e += 64) {
        const int n = min(64, e1 - e);
        const int myS = (lane < n) ? esrc[e + lane] : 0;
        for (int j = 0; j < n; ++j) {
            const int s = __shfl(myS, j);
            const float2 v = ((const float2*)(x + (size_t)s * D_IN))[lane];
            acc.x += v.x;
            acc.y += v.y;
        }
    }
    ((float2*)(agg + (size_t)node * D_IN))[lane] = acc;
}

// h1 = (x+agg) @ W1 + b1, plus per-column sum / sumsq partials for BN.
__global__ __launch_bounds__(256) void gemm1_kernel(
    const float* __restrict__ x, const float* __restrict__ agg,
    const float* __restrict__ W1, const float* __restrict__ b1,
    float* __restrict__ h1, float* __restrict__ ssum, float* __restrict__ ssq)
{
    __shared__ float As[D_IN][BM];   // A transposed: As[k][i]
    __shared__ float Bs[D_IN][BN];   // Bs[k][j]
    const int tid = threadIdx.x;
    const int i0 = blockIdx.x * BM;
    const int jb = blockIdx.y * BN;

    // ---- stage A = (x+agg)^T via 4x4 register transpose ----
    {
        const int r4 = (tid & 15) * 4;
        const int c8 = (tid >> 4) * 4;
        #pragma unroll
        for (int cc = 0; cc < 2; ++cc) {
            const int c = c8 + cc * 64;
            float4 v[4];
            #pragma unroll
            for (int q = 0; q < 4; ++q) {
                const int row = i0 + r4 + q;
                if (row < N_NODES) {
                    const float4 xv = *(const float4*)(x   + (size_t)row * D_IN + c);
                    const float4 av = *(const float4*)(agg + (size_t)row * D_IN + c);
                    v[q] = make_float4(xv.x+av.x, xv.y+av.y, xv.z+av.z, xv.w+av.w);
                } else {
                    v[q] = make_float4(0.f, 0.f, 0.f, 0.f);
                }
            }
            *(float4*)&As[c+0][r4] = make_float4(v[0].x, v[1].x, v[2].x, v[3].x);
            *(float4*)&As[c+1][r4] = make_float4(v[0].y, v[1].y, v[2].y, v[3].y);
            *(float4*)&As[c+2][r4] = make_float4(v[0].z, v[1].z, v[2].z, v[3].z);
            *(float4*)&As[c+3][r4] = make_float4(v[0].w, v[1].w, v[2].w, v[3].w);
        }
    }
    // ---- stage B = W1[:, jb:jb+64] ----
    {
        const int j4 = (tid & 15) * 4;
        const int k0 = tid >> 4;
        #pragma unroll
        for (int kk = 0; kk < 8; ++kk) {
            const int k = k0 + kk * 16;
            *(float4*)&Bs[k][j4] = *(const float4*)(W1 + (size_t)k * D_HID + jb + j4);
        }
    }
    __syncthreads();

    const int tx = tid & 15, ty = tid >> 4;
    const int ay = ty * 4, bx = tx * 4;
    float acc[4][4];
    #pragma unroll
    for (int r = 0; r < 4; ++r)
        #pragma unroll
        for (int q = 0; q < 4; ++q) acc[r][q] = 0.f;

    #pragma unroll 4
    for (int k = 0; k < D_IN; ++k) {
        const float4 a = *(const float4*)&As[k][ay];
        const float4 b = *(const float4*)&Bs[k][bx];
        const float ar[4] = {a.x, a.y, a.z, a.w};
        const float br[4] = {b.x, b.y, b.z, b.w};
        #pragma unroll
        for (int r = 0; r < 4; ++r)
            #pragma unroll
            for (int q = 0; q < 4; ++q)
                acc[r][q] = fmaf(ar[r], br[q], acc[r][q]);
    }

    // ---- epilogue: bias, store h1, per-col partial stats ----
    const float4 b1v = *(const float4*)(b1 + jb + bx);
    const float bvv[4] = {b1v.x, b1v.y, b1v.z, b1v.w};
    float s[4] = {0.f,0.f,0.f,0.f}, sq[4] = {0.f,0.f,0.f,0.f};
    #pragma unroll
    for (int r = 0; r < 4; ++r) {
        const int row = i0 + ay + r;
        if (row < N_NODES) {
            float hv[4];
            #pragma unroll
            for (int q = 0; q < 4; ++q) hv[q] = acc[r][q] + bvv[q];
            *(float4*)(h1 + (size_t)row * D_HID + jb + bx) =
                make_float4(hv[0], hv[1], hv[2], hv[3]);
            #pragma unroll
            for (int q = 0; q < 4; ++q) { s[q] += hv[q]; sq[q] += hv[q]*hv[q]; }
        }
    }
    __syncthreads();                    // reuse As as reduction scratch
    float* red = &As[0][0];             // needs 2*64*16 = 2048 floats
    #pragma unroll
    for (int q = 0; q < 4; ++q) {
        red[(bx + q) * 16 + ty]        = s[q];
        red[1024 + (bx + q) * 16 + ty] = sq[q];
    }
    __syncthreads();
    if (tid < 64) {
        float a0 = 0.f, a1 = 0.f;
        #pragma unroll
        for (int t = 0; t < 16; ++t) {
            a0 += red[tid * 16 + t];
            a1 += red[1024 + tid * 16 + t];
        }
        atomicAdd(&ssum[jb + tid], a0);
        atomicAdd(&ssq [jb + tid], a1);
    }
}

__global__ __launch_bounds__(256) void bnfinal_kernel(
    const float* __restrict__ ssum, const float* __restrict__ ssq,
    const float* __restrict__ gamma, const float* __restrict__ beta,
    float* __restrict__ aco, float* __restrict__ cco)
{
    const int j = threadIdx.x;
    const float inv_n = 1.0f / (float)N_NODES;
    const float mean = ssum[j] * inv_n;
    const float var  = ssq[j] * inv_n - mean * mean;
    const float rstd = rsqrtf(var + BN_EPS);
    const float a = rstd * gamma[j];
    aco[j] = a;
    cco[j] = beta[j] - mean * a;
}

// out = relu(h1*a + c) @ W2 + b2
__global__ __launch_bounds__(256) void gemm2_kernel(
    const float* __restrict__ h1, const float* __restrict__ W2,
    const float* __restrict__ b2,
    const float* __restrict__ aco, const float* __restrict__ cco,
    float* __restrict__ out)
{
    __shared__ float As[128][BM];
    __shared__ float Bs[128][BN];
    const int tid = threadIdx.x;
    const int i0 = blockIdx.x * BM;
    const int jb = blockIdx.y * BN;
    const int tx = tid & 15, ty = tid >> 4;
    const int ay = ty * 4, bx = tx * 4;

    float acc[4][4];
    #pragma unroll
    for (int r = 0; r < 4; ++r)
        #pragma unroll
        for (int q = 0; q < 4; ++q) acc[r][q] = 0.f;

    for (int kk = 0; kk < 2; ++kk) {
        if (kk) __syncthreads();
        // ---- stage A chunk: relu(h1*a + c), transposed ----
        {
            const int r4 = (tid & 15) * 4;
            const int c8 = (tid >> 4) * 4;
            #pragma unroll
            for (int cc = 0; cc < 2; ++cc) {
                const int c  = c8 + cc * 64;
                const int gc = kk * 128 + c;
                const float4 a4 = *(const float4*)(aco + gc);
                const float4 c4 = *(const float4*)(cco + gc);
                float4 v[4];
                #pragma unroll
                for (int q = 0; q < 4; ++q) {
                    const int row = i0 + r4 + q;
                    if (row < N_NODES) {
                        const float4 hv = *(const float4*)(h1 + (size_t)row * D_HID + gc);
                        v[q] = make_float4(fmaxf(fmaf(hv.x, a4.x, c4.x), 0.f),
                                           fmaxf(fmaf(hv.y, a4.y, c4.y), 0.f),
                                           fmaxf(fmaf(hv.z, a4.z, c4.z), 0.f),
                                           fmaxf(fmaf(hv.w, a4.w, c4.w), 0.f));
                    } else {
                        v[q] = make_float4(0.f, 0.f, 0.f, 0.f);
                    }
                }
                *(float4*)&As[c+0][r4] = make_float4(v[0].x, v[1].x, v[2].x, v[3].x);
                *(float4*)&As[c+1][r4] = make_float4(v[0].y, v[1].y, v[2].y, v[3].y);
                *(float4*)&As[c+2][r4] = make_float4(v[0].z, v[1].z, v[2].z, v[3].z);
                *(float4*)&As[c+3][r4] = make_float4(v[0].w, v[1].w, v[2].w, v[3].w);
            }
        }
        // ---- stage B chunk: W2[kk*128 : +128, jb : jb+64] ----
        {
            const int j4 = (tid & 15) * 4;
            const int k0 = tid >> 4;
            #pragma unroll
            for (int kx = 0; kx < 8; ++kx) {
                const int k = k0 + kx * 16;
                *(float4*)&Bs[k][j4] =
                    *(const float4*)(W2 + (size_t)(kk * 128 + k) * D_OUT + jb + j4);
            }
        }
        __syncthreads();

        #pragma unroll 4
        for (int k = 0; k < 128; ++k) {
            const float4 a = *(const float4*)&As[k][ay];
            const float4 b = *(const float4*)&Bs[k][bx];
            const float ar[4] = {a.x, a.y, a.z, a.w};
            const float br[4] = {b.x, b.y, b.z, b.w};
            #pragma unroll
            for (int r = 0; r < 4; ++r)
                #pragma unroll
                for (int q = 0; q < 4; ++q)
                    acc[r][q] = fmaf(ar[r], br[q], acc[r][q]);
        }
    }

    const float4 b2v = *(const float4*)(b2 + jb + bx);
    #pragma unroll
    for (int r = 0; r < 4; ++r) {
        const int row = i0 + ay + r;
        if (row < N_NODES) {
            *(float4*)(out + (size_t)row * D_OUT + jb + bx) =
                make_float4(acc[r][0] + b2v.x, acc[r][1] + b2v.y,
                            acc[r][2] + b2v.z, acc[r][3] + b2v.w);
        }
    }
}

extern "C" void kernel_launch(void* const* d_in, const int* in_sizes, int n_in,
                              void* d_out, int out_size, void* d_ws, size_t ws_size,
                              hipStream_t stream)
{
    const float* x     = (const float*)d_in[0];
    const int*   ei    = (const int*)d_in[1];      // int32 per harness contract
    const float* W1    = (const float*)d_in[2];
    const float* b1    = (const float*)d_in[3];
    const float* gamma = (const float*)d_in[4];
    const float* beta  = (const float*)d_in[5];
    const float* W2    = (const float*)d_in[6];
    const float* b2    = (const float*)d_in[7];
    float* out = (float*)d_out;

    // workspace layout (floats/ints):
    // agg[N*128] | h1[N*256] | ssum[256] | ssq[256] | aco[256] | cco[256]
    // | deg[N] | off[N+1] | cursor[N] | esrc[E] | bsum[64]
    float* agg  = (float*)d_ws;
    float* h1   = agg + (size_t)N_NODES * D_IN;
    float* ssum = h1  + (size_t)N_NODES * D_HID;
    float* ssq  = ssum + D_HID;
    float* aco  = ssq  + D_HID;
    float* cco  = aco  + D_HID;
    int* deg    = (int*)(cco + D_HID);
    int* off    = deg + N_NODES;
    int* cursor = off + N_NODES + 1;
    int* esrc   = cursor + N_NODES;
    int* bsum   = esrc + N_EDGES;

    hipMemsetAsync(deg,  0, N_NODES * sizeof(int), stream);
    hipMemsetAsync(ssum, 0, 2 * D_HID * sizeof(float), stream);

    deg_kernel<<<(N_EDGES + 255) / 256, 256, 0, stream>>>(ei, deg);
    scan1_kernel<<<NBLK_SCAN, 256, 0, stream>>>(deg, bsum);
    scan2_kernel<<<1, 64, 0, stream>>>(bsum, off);
    scan3_kernel<<<NBLK_SCAN, 256, 0, stream>>>(deg, bsum, off, cursor);
    fill_kernel<<<(N_EDGES + 255) / 256, 256, 0, stream>>>(ei, cursor, esrc);
    gather_kernel<<<(N_NODES * 64 + 255) / 256, 256, 0, stream>>>(x, off, esrc, agg);

    gemm1_kernel<<<dim3((N_NODES + BM - 1) / BM, D_HID / BN), 256, 0, stream>>>(
        x, agg, W1, b1, h1, ssum, ssq);

    bnfinal_kernel<<<1, D_HID, 0, stream>>>(ssum, ssq, gamma, beta, aco, cco);

    gemm2_kernel<<<dim3((N_NODES + BM - 1) / BM, D_OUT / BN), 256, 0, stream>>>(
        h1, W2, b2, aco, cco, out);
}